// Round 1
// baseline (225.198 us; speedup 1.0000x reference)
//
#include <hip/hip_runtime.h>

#define NKEYS 64

// out[i] = t[x[i]] where t is a 64-entry table derived from (keys, b):
//   t[v] = b[k] if keys[k] == (float)v for integral v in [0,64), else 0.
// Inputs are int32 in [0,64) per the reference; out-of-range values -> 0.
__global__ __launch_bounds__(256) void sel_xform_kernel(
    const int4* __restrict__ in,
    const float* __restrict__ b,
    const float* __restrict__ keys,
    float4* __restrict__ out,
    int nvec, int ntail, const int* __restrict__ in_tail, float* __restrict__ out_tail)
{
    __shared__ float t[NKEYS];
    const int tid = threadIdx.x;
    if (tid < NKEYS) t[tid] = 0.0f;
    __syncthreads();
    if (tid < NKEYS) {
        const float kv = keys[tid];
        const int iv = (int)kv;
        if ((float)iv == kv && iv >= 0 && iv < NKEYS) {
            t[iv] = b[tid];   // keys are unique -> no write race
        }
    }
    __syncthreads();

    int i = blockIdx.x * blockDim.x + tid;
    const int stride = gridDim.x * blockDim.x;
    for (; i < nvec; i += stride) {
        const int4 v = in[i];
        float4 o;
        o.x = ((unsigned)v.x < NKEYS) ? t[v.x] : 0.0f;
        o.y = ((unsigned)v.y < NKEYS) ? t[v.y] : 0.0f;
        o.z = ((unsigned)v.z < NKEYS) ? t[v.z] : 0.0f;
        o.w = ((unsigned)v.w < NKEYS) ? t[v.w] : 0.0f;
        out[i] = o;
    }

    // Scalar tail (n % 4 elements), handled by the first few threads of block 0.
    if (blockIdx.x == 0 && tid < ntail) {
        const int v = in_tail[tid];
        out_tail[tid] = ((unsigned)v < NKEYS) ? t[v] : 0.0f;
    }
}

extern "C" void kernel_launch(void* const* d_in, const int* in_sizes, int n_in,
                              void* d_out, int out_size, void* d_ws, size_t ws_size,
                              hipStream_t stream) {
    const int*   x    = (const int*)d_in[0];     // inputs, int32, [8,4096,1024]
    const float* b    = (const float*)d_in[1];   // per-key bias, [64]
    const float* keys = (const float*)d_in[2];   // sorted unique keys, [64]
    float* out = (float*)d_out;

    const int n    = in_sizes[0];
    const int nvec = n >> 2;        // int4 / float4 groups
    const int ntail = n & 3;

    const int block = 256;
    int grid = (nvec + block - 1) / block;
    if (grid < 1) grid = 1;

    sel_xform_kernel<<<grid, block, 0, stream>>>(
        (const int4*)x, b, keys, (float4*)out,
        nvec, ntail, x + (nvec << 2), out + (nvec << 2));
}